// Round 4
// baseline (4708.250 us; speedup 1.0000x reference)
//
#include <hip/hip_runtime.h>
#include <math.h>

// Problem dims (reference: N, Fin, E, H1, H2 = 128, 512, 128, 256, 128)
constexpr int Nn  = 128;   // nodes
constexpr int FIN = 512;   // input feature dim
constexpr int EE  = 128;   // embed dim E
constexpr int TWO_E = 256; // 2E (W1 rows)
constexpr int H1n = 256;   // hidden 1
constexpr int H2n = 128;   // hidden 2

// ---------------------------------------------------------------------------
// Precompute 1: G0 = feature_origin @ W_e (pre-bias, pre-relu)   [128][128]
//               feat = relu(G0 + b_e)   (feat lives in d_out)
// grid 128 x 128
// ---------------------------------------------------------------------------
__global__ void precomp1(const float* __restrict__ fo, const float* __restrict__ We,
                         const float* __restrict__ be,
                         float* __restrict__ G0, float* __restrict__ feat)
{
    const int n = blockIdx.x;
    const int j = threadIdx.x;        // 0..127
    float acc = 0.f;
    for (int k = 0; k < FIN; ++k)
        acc += fo[n * FIN + k] * We[k * EE + j];
    G0[n * EE + j] = acc;
    feat[n * EE + j] = fmaxf(acc + be[j], 0.f);
}

// ---------------------------------------------------------------------------
// Precompute 2: Bcur[n] = relu(G0[n]+be) @ W1_bot (rows 128..255)  [128][256]
//               B0 = Bcur if B0 != nullptr
// grid 128 x 256
// ---------------------------------------------------------------------------
__global__ void precomp2(const float* __restrict__ G0, const float* __restrict__ be,
                         const float* __restrict__ W1,
                         float* __restrict__ Bcur, float* __restrict__ B0)
{
    __shared__ float f[EE];
    const int n = blockIdx.x;
    const int j = threadIdx.x;        // 0..255
    if (j < EE) f[j] = fmaxf(G0[n * EE + j] + be[j], 0.f);
    __syncthreads();
    float acc = 0.f;
    for (int k = 0; k < EE; ++k)
        acc += f[k] * W1[(EE + k) * H1n + j];
    Bcur[n * H1n + j] = acc;
    if (B0) B0[n * H1n + j] = acc;
}

// ---------------------------------------------------------------------------
// Sequential policy kernel: single block, 1024 threads.
// State: feat[128][128] (== d_out), Bcur[128][256]; const G0[128][128].
// Per step:
//   P1: u = [x@W1_top | x@W1_bot]  (512-wide; B half only if i is a candidate)
//   P2: rows = cand(<=3)+sentinel: h1=relu(u_a+B'+b1)[256]; h2=relu(h1@W2+b2)[128]
//       (B' = 0 for row 0 and sentinel — reference's `v > 0` quirk); lk = h2.wlk
//   P3: first-max argmax over [candidates.., sentinel]; at = (act1 > act0);
//       feat[i]=relu((gsum + at*G0[utc] + G0[i])/(cnt+at+1) + be);
//       feat[utc]=relu(G0[utc]+be); Bcur[utc]=B0[utc] (or recompute);
//       utc==i -> the utc-reset wins (reference .at[i].set().at[utc].set()).
// ---------------------------------------------------------------------------
__global__ __launch_bounds__(1024) void seqk(
    const float* __restrict__ adj,  const float* __restrict__ W1,
    const float* __restrict__ b1,   const float* __restrict__ W2,
    const float* __restrict__ b2,   const float* __restrict__ wlk,
    const float* __restrict__ blkb, const float* __restrict__ wact,
    const float* __restrict__ bact, const float* __restrict__ be,
    const float* __restrict__ G0,   const float* __restrict__ B0,
    float* __restrict__ feat,       float* __restrict__ Bcur)
{
    __shared__ float x[EE];            // current feature[i] (128)
    __shared__ float u[2 * H1n];       // [a(256) | B_i(256)]
    __shared__ float pacc[8][512];     // partial accumulators (also used as [16][256])
    __shared__ float h1[4][H1n];
    __shared__ float h2[4][H2n];
    __shared__ float lkv[4];
    __shared__ float gsum[EE];         // sum of G0 rows currently in sel
    __shared__ float rowf[EE];         // relu(G0[utc]+be) of current step
    __shared__ float sbe[EE];          // staged b_e
    __shared__ float redbuf[8];
    __shared__ int   candlist[4];
    __shared__ unsigned long long cand_mask[2], sel_mask[2], upd_mask[2];
    __shared__ int   ncand_s, ut_s, at_s, brk_s, rr_s, needb_s, xdirty_s;
    __shared__ float cnt_s;

    const int tid = threadIdx.x;
    float* pflat = &pacc[0][0];        // 4096 floats
    if (tid < 2) upd_mask[tid] = 0ULL;
    if (tid < EE) sbe[tid] = be[tid];

    for (int i = 0; i < Nn; ++i) {
        // ---- node init ----
        if (tid < EE) gsum[tid] = 0.f;
        if (tid == 0) { cnt_s = 0.f; sel_mask[0] = 0ULL; sel_mask[1] = 0ULL; xdirty_s = 0; }
        if (tid < Nn) {
            const bool c = adj[i * Nn + tid] != 0.f;
            const unsigned long long m = __ballot(c);
            if ((tid & 63) == 0) cand_mask[tid >> 6] = m;
        }
        if (tid < EE) x[tid] = feat[i * EE + tid];
        __syncthreads();
        if (tid == 0) {
            int nc = 0, selfc = 0;
            for (int w = 0; w < 2; ++w) {
                unsigned long long m = cand_mask[w];
                while (m && nc < 4) {
                    const int b = __builtin_ctzll(m);
                    const int v = w * 64 + b;
                    candlist[nc++] = v;
                    if (v == i) selfc = 1;
                    m &= m - 1;
                }
            }
            ncand_s = nc; needb_s = selfc;
        }
        __syncthreads();

        for (int s = 0; s < 4; ++s) {
            // ---------- Phase 1: u = x @ [W1_top | W1_bot] (k-depth 128) ----------
            {
                const int ks = tid >> 7;       // 0..7 k-slice (16 k each)
                const int cg = tid & 127;      // col group: 0..63 -> a, 64..127 -> B
                const bool bpart = (cg >= 64);
                float4 a4 = make_float4(0.f, 0.f, 0.f, 0.f);
                if (!bpart || needb_s) {
                    const float* wb = W1 + (bpart ? (EE * H1n + (cg - 64) * 4) : (cg * 4));
                    for (int kk = 0; kk < 16; ++kk) {
                        const int k = ks * 16 + kk;
                        const float xk = x[k];
                        if (xk != 0.f) {
                            const float4 w = *reinterpret_cast<const float4*>(wb + k * H1n);
                            a4.x += xk * w.x; a4.y += xk * w.y;
                            a4.z += xk * w.z; a4.w += xk * w.w;
                        }
                    }
                }
                float* pr = &pacc[ks][cg * 4];
                pr[0] = a4.x; pr[1] = a4.y; pr[2] = a4.z; pr[3] = a4.w;
            }
            __syncthreads();
            if (tid < 512) {
                float v = 0.f;
                #pragma unroll
                for (int q = 0; q < 8; ++q) v += pacc[q][tid];
                u[tid] = v;
                if (tid >= 256 && needb_s) Bcur[i * H1n + (tid - 256)] = v;
            }
            __syncthreads();

            // ---------- Phase 2: rows = cand + sentinel ----------
            const int nrows = ncand_s + 1;
            {
                const int r = tid >> 8, k = tid & 255;   // 4 x 256
                if (r < nrows) {
                    const int v = (r < ncand_s) ? candlist[r] : -1;    // -1 = sentinel
                    const float Bv = (v > 0) ? Bcur[v * H1n + k] : 0.f; // v==0 quirk -> 0
                    h1[r][k] = fmaxf(u[k] + Bv + b1[k], 0.f);
                }
            }
            __syncthreads();
            {
                const int ks = tid >> 7, rem = tid & 127;
                const int rr = rem >> 5, cg = rem & 31;  // 8 kslices x 4 rows x 32 cgroups
                float4 a4 = make_float4(0.f, 0.f, 0.f, 0.f);
                if (rr < nrows) {
                    for (int kk = 0; kk < 32; ++kk) {
                        const int k = ks * 32 + kk;      // k-depth 256
                        const float h = h1[rr][k];
                        const float4 w = *reinterpret_cast<const float4*>(W2 + k * H2n + cg * 4);
                        a4.x += h * w.x; a4.y += h * w.y;
                        a4.z += h * w.z; a4.w += h * w.w;
                    }
                }
                float* pr = &pacc[ks][rr * H2n + cg * 4];
                pr[0] = a4.x; pr[1] = a4.y; pr[2] = a4.z; pr[3] = a4.w;
            }
            __syncthreads();
            if (tid < 512) {
                const int rr = tid >> 7, jj = tid & 127;
                float v = 0.f;
                #pragma unroll
                for (int q = 0; q < 8; ++q) v += pacc[q][tid];
                const float hval = (rr < nrows) ? fmaxf(v + b2[jj], 0.f) : 0.f;
                h2[rr][jj] = hval;
                float p = hval * wlk[jj];
                #pragma unroll
                for (int off = 32; off; off >>= 1) p += __shfl_down(p, off);
                if ((tid & 63) == 0) redbuf[tid >> 6] = p;
            }
            __syncthreads();
            if (tid < 4) lkv[tid] = redbuf[2 * tid] + redbuf[2 * tid + 1] + blkb[0];
            __syncthreads();

            // ---------- Phase 3: argmax (index order, first-max wins) ----------
            if (tid == 0) {
                float bv = -INFINITY; int ut = -1;
                for (int r2 = 0; r2 < ncand_s; ++r2)
                    if (lkv[r2] > bv) { bv = lkv[r2]; ut = candlist[r2]; }
                if (ut < 0 || lkv[ncand_s] > bv) ut = Nn;   // sentinel
                ut_s = ut;
                brk_s = (ut == Nn);
                if (!brk_s) {
                    int rr = 0;
                    for (int r2 = 0; r2 < ncand_s; ++r2)
                        if (candlist[r2] == ut) rr = r2;
                    rr_s = rr;
                }
            }
            __syncthreads();
            if (brk_s) break;   // uniform: is_end -> done for remaining steps

            // action head: at = (h2[utc].wa1+ba1 > h2[utc].wa0+ba0)
            if (tid < 256) {
                const int jj = tid & 127, col = tid >> 7;
                float p = h2[rr_s][jj] * wact[jj * 2 + col];
                #pragma unroll
                for (int off = 32; off; off >>= 1) p += __shfl_down(p, off);
                if ((tid & 63) == 0) redbuf[4 + (tid >> 6)] = p;
            }
            __syncthreads();
            if (tid == 0) {
                const float a0 = redbuf[4] + redbuf[5] + bact[0];
                const float a1 = redbuf[6] + redbuf[7] + bact[1];
                at_s = (a1 > a0) ? 1 : 0;
            }
            __syncthreads();

            // ---- state update: wide part ----
            {
                const int utc = ut_s;
                const float at = (float)at_s;
                const bool selOld = (sel_mask[utc >> 6] >> (utc & 63)) & 1ULL;
                const float denom = cnt_s + at + 1.0f;
                if (tid < EE) {
                    const float g_ut = G0[utc * EE + tid];
                    const float futc = fmaxf(g_ut + sbe[tid], 0.f); // F0[utc] on the fly
                    const float z = (gsum[tid] + at * g_ut + G0[i * EE + tid]) / denom
                                    + sbe[tid];
                    float nx = fmaxf(z, 0.f);
                    if (utc == i) nx = futc;                 // .at[utc] write wins
                    x[tid] = nx;
                    if (utc != i) feat[i * EE + tid] = nx;
                    feat[utc * EE + tid] = futc;
                    rowf[tid] = futc;
                    if (at_s && !selOld) gsum[tid] += g_ut;
                }
                if (B0 != nullptr && tid < H1n)
                    Bcur[utc * H1n + tid] = B0[utc * H1n + tid];
            }
            __syncthreads();
            // ---- state update: scalar part ----
            if (tid == 0) {
                const int utc = ut_s;
                const bool selOld = (sel_mask[utc >> 6] >> (utc & 63)) & 1ULL;
                if (at_s && !selOld) { cnt_s += 1.f; sel_mask[utc >> 6] |= (1ULL << (utc & 63)); }
                cand_mask[utc >> 6] &= ~(1ULL << (utc & 63));
                upd_mask[i >> 6]   |= (1ULL << (i & 63));
                upd_mask[utc >> 6] |= (1ULL << (utc & 63));
                xdirty_s = (utc != i) ? 1 : 0;
                int nc = 0, selfc = 0;
                for (int w = 0; w < 2; ++w) {
                    unsigned long long m = cand_mask[w];
                    while (m && nc < 4) {
                        const int b = __builtin_ctzll(m);
                        const int v = w * 64 + b;
                        candlist[nc++] = v;
                        if (v == i) selfc = 1;
                        m &= m - 1;
                    }
                }
                ncand_s = nc; needb_s = selfc;
            }
            __syncthreads();

            // ---- Bcur[utc] reset without B0 cache: recompute from rowf ----
            if (B0 == nullptr) {
                {
                    const int ks = tid >> 6, cg = tid & 63;   // 16 kslices x 64 cgroups
                    float4 a4 = make_float4(0.f, 0.f, 0.f, 0.f);
                    for (int kk = 0; kk < 8; ++kk) {
                        const int k = ks * 8 + kk;            // k-depth 128
                        const float f = rowf[k];
                        if (f != 0.f) {
                            const float4 w = *reinterpret_cast<const float4*>(W1 + (EE + k) * H1n + cg * 4);
                            a4.x += f * w.x; a4.y += f * w.y;
                            a4.z += f * w.z; a4.w += f * w.w;
                        }
                    }
                    float* pr = &pflat[ks * H1n + cg * 4];
                    pr[0] = a4.x; pr[1] = a4.y; pr[2] = a4.z; pr[3] = a4.w;
                }
                __syncthreads();
                if (tid < H1n) {
                    float v = 0.f;
                    #pragma unroll
                    for (int q = 0; q < 16; ++q) v += pflat[q * H1n + tid];
                    Bcur[ut_s * H1n + tid] = v;
                }
                __syncthreads();
            }
        } // steps

        // node end: feature[i] left as embed(hv) -> refresh Bcur[i]
        if (xdirty_s) {
            {
                const int ks = tid >> 6, cg = tid & 63;
                float4 a4 = make_float4(0.f, 0.f, 0.f, 0.f);
                for (int kk = 0; kk < 8; ++kk) {
                    const int k = ks * 8 + kk;
                    const float xk = x[k];
                    if (xk != 0.f) {
                        const float4 w = *reinterpret_cast<const float4*>(W1 + (EE + k) * H1n + cg * 4);
                        a4.x += xk * w.x; a4.y += xk * w.y;
                        a4.z += xk * w.z; a4.w += xk * w.w;
                    }
                }
                float* pr = &pflat[ks * H1n + cg * 4];
                pr[0] = a4.x; pr[1] = a4.y; pr[2] = a4.z; pr[3] = a4.w;
            }
            __syncthreads();
            if (tid < H1n) {
                float v = 0.f;
                #pragma unroll
                for (int q = 0; q < 16; ++q) v += pflat[q * H1n + tid];
                Bcur[i * H1n + tid] = v;
            }
        }
        __syncthreads();
    } // nodes

    // out = where(updated, feat, 0) — in place on d_out
    for (int idx = tid; idx < Nn * EE; idx += 1024) {
        const int n = idx >> 7;   // EE = 128
        const float v = feat[idx];
        feat[idx] = ((upd_mask[n >> 6] >> (n & 63)) & 1ULL) ? v : 0.f;
    }
}

// ---------------------------------------------------------------------------
extern "C" void kernel_launch(void* const* d_in, const int* in_sizes, int n_in,
                              void* d_out, int out_size, void* d_ws, size_t ws_size,
                              hipStream_t stream)
{
    (void)in_sizes; (void)n_in; (void)out_size;
    const float* adj  = (const float*)d_in[0];
    const float* fo   = (const float*)d_in[1];
    // d_in[2] = labels (unused by the forward pass)
    const float* We   = (const float*)d_in[3];
    const float* be   = (const float*)d_in[4];
    const float* W1   = (const float*)d_in[5];
    const float* b1   = (const float*)d_in[6];
    const float* W2   = (const float*)d_in[7];
    const float* b2   = (const float*)d_in[8];
    const float* wlk  = (const float*)d_in[9];
    const float* blkb = (const float*)d_in[10];
    const float* wact = (const float*)d_in[11];
    const float* bact = (const float*)d_in[12];

    float* ws   = (float*)d_ws;
    float* G0   = ws;                 // 128*128 floats (64 KB)
    float* Bcur = ws + 16384;         // 128*256 floats (128 KB)
    // Optional reset cache only if workspace is large enough (320 KB total)
    float* B0   = (ws_size >= (size_t)(64 + 128 + 128) * 1024) ? (ws + 49152) : nullptr;
    float* feat = (float*)d_out;      // evolving feature table lives in d_out (64 KB)

    hipLaunchKernelGGL(precomp1, dim3(Nn), dim3(EE), 0, stream, fo, We, be, G0, feat);
    hipLaunchKernelGGL(precomp2, dim3(Nn), dim3(H1n), 0, stream, G0, be, W1, Bcur, B0);
    hipLaunchKernelGGL(seqk, dim3(1), dim3(1024), 0, stream,
                       adj, W1, b1, W2, b2, wlk, blkb, wact, bact, be,
                       G0, B0, feat, Bcur);
}

// Round 6
// 1969.562 us; speedup vs baseline: 2.3905x; 2.3905x over previous
//
#include <hip/hip_runtime.h>
#include <math.h>

// Problem dims (reference: N, Fin, E, H1, H2 = 128, 512, 128, 256, 128)
constexpr int Nn  = 128;   // nodes
constexpr int FIN = 512;   // input feature dim
constexpr int EE  = 128;   // embed dim E
constexpr int H1n = 256;   // hidden 1 (= 2E = W1 rows, coincidentally)
constexpr int H2n = 128;   // hidden 2

// ---------------------------------------------------------------------------
// Precompute 1: G0 = feature_origin @ W_e (pre-bias, pre-relu)   [128][128]
//               feat = relu(G0 + b_e)   (feat lives in d_out)
// ---------------------------------------------------------------------------
__global__ void precomp1(const float* __restrict__ fo, const float* __restrict__ We,
                         const float* __restrict__ be,
                         float* __restrict__ G0, float* __restrict__ feat)
{
    const int n = blockIdx.x;
    const int j = threadIdx.x;        // 0..127
    float acc = 0.f;
    for (int k = 0; k < FIN; ++k)
        acc += fo[n * FIN + k] * We[k * EE + j];
    G0[n * EE + j] = acc;
    feat[n * EE + j] = fmaxf(acc + be[j], 0.f);
}

// ---------------------------------------------------------------------------
// Precompute 2: Bcur[n] = relu(G0[n]+be) @ W1_bot (rows 128..255)  [128][256]
//               B0 = Bcur if B0 != nullptr
// ---------------------------------------------------------------------------
__global__ void precomp2(const float* __restrict__ G0, const float* __restrict__ be,
                         const float* __restrict__ W1,
                         float* __restrict__ Bcur, float* __restrict__ B0)
{
    __shared__ float f[EE];
    const int n = blockIdx.x;
    const int j = threadIdx.x;        // 0..255
    if (j < EE) f[j] = fmaxf(G0[n * EE + j] + be[j], 0.f);
    __syncthreads();
    float acc = 0.f;
    for (int k = 0; k < EE; ++k)
        acc += f[k] * W1[(EE + k) * H1n + j];
    Bcur[n * H1n + j] = acc;
    if (B0) B0[n * H1n + j] = acc;
}

// ---------------------------------------------------------------------------
// Sequential policy kernel: ONE block, 512 threads, weights persistent:
//   W1 (256KB) in registers: thread t<256 holds W1_top col t (128 floats);
//                            thread t>=256 holds W1_bot col t-256.
//   W2 (128KB) in LDS, transposed + XOR-swizzled (16B-group ^ (j&7)).
// 7 barriers/step. Bcur stays global (3KB/step reads); u_B cached in LDS.
// ---------------------------------------------------------------------------
__global__ __launch_bounds__(512, 2) void seqk(
    const float* __restrict__ adj,  const float* __restrict__ W1,
    const float* __restrict__ b1,   const float* __restrict__ W2,
    const float* __restrict__ b2,   const float* __restrict__ wlk,
    const float* __restrict__ blkb, const float* __restrict__ wact,
    const float* __restrict__ bact, const float* __restrict__ be,
    const float* __restrict__ G0,   const float* __restrict__ B0,
    float* __restrict__ feat,       float* __restrict__ Bcur)
{
    __shared__ float w2t[H2n * H1n];   // 128KB: w2t[j][k-swizzled] = W2[k][j]
    __shared__ float x[EE];            // current feature[i]
    __shared__ float u[H1n];           // a-half: x @ W1_top
    __shared__ float ubi[H1n];         // B_i = x @ W1_bot (valid when needb)
    __shared__ float h1[4][H1n];
    __shared__ float h2[4][H2n];
    __shared__ float pa[4][4][H2n];    // [kq][r][j] partials
    __shared__ float gsum[EE], rowf[EE], sbe[EE];
    __shared__ float sb1[H1n], sb2[H2n], swlk[H2n], swact[2 * H2n];
    __shared__ float rb_lk[8], rb_a0[8], rb_a1[8];
    __shared__ float sblk, sba0, sba1;
    __shared__ int   candlist[4];
    __shared__ unsigned long long cand_mask[2], sel_mask[2], upd_mask[2];
    __shared__ int   ncand_s, ut_s, at_s, brk_s, rr_s, needb_s, xdirty_s;
    __shared__ float cnt_s;

    const int tid = threadIdx.x;

    // ---- prologue: persistent weights ----
    float w1reg[128];                  // one W1 column per thread
    {
        const int col = tid & 255;
        const int rbase = (tid < 256) ? 0 : EE;
        #pragma unroll
        for (int k = 0; k < 128; ++k)
            w1reg[k] = W1[(rbase + k) * H1n + col];
    }
    for (int idx = tid; idx < H1n * H2n; idx += 512) {
        const int k = idx >> 7, j = idx & 127;      // coalesced read of W2 row k
        const int cg = k >> 2, w = k & 3;
        w2t[j * H1n + (((cg ^ (j & 7)) << 2) | w)] = W2[k * H2n + j];
    }
    if (tid < EE)  sbe[tid] = be[tid];
    if (tid < H1n) sb1[tid] = b1[tid];
    if (tid < H2n) { sb2[tid] = b2[tid]; swlk[tid] = wlk[tid]; }
    if (tid < 2 * H2n) swact[tid] = wact[tid];
    if (tid == 0) { sblk = blkb[0]; sba0 = bact[0]; sba1 = bact[1]; }
    if (tid < 2) upd_mask[tid] = 0ULL;
    __syncthreads();

    for (int i = 0; i < Nn; ++i) {
        // ---- node init ----
        if (tid < EE) { gsum[tid] = 0.f; x[tid] = feat[i * EE + tid]; }
        if (tid == 0) { cnt_s = 0.f; sel_mask[0] = 0ULL; sel_mask[1] = 0ULL; xdirty_s = 0; }
        if (tid < Nn) {
            const bool c = adj[i * Nn + tid] != 0.f;
            const unsigned long long m = __ballot(c);
            if ((tid & 63) == 0) cand_mask[tid >> 6] = m;
        }
        __syncthreads();
        if (tid == 0) {
            int nc = 0, selfc = 0;
            for (int w = 0; w < 2; ++w) {
                unsigned long long m = cand_mask[w];
                while (m && nc < 4) {
                    const int b = __builtin_ctzll(m);
                    const int v = w * 64 + b;
                    candlist[nc++] = v;
                    if (v == i) selfc = 1;
                    m &= m - 1;
                }
            }
            ncand_s = nc; needb_s = selfc;
        }
        __syncthreads();

        for (int s = 0; s < 4; ++s) {
            // ---- P1: u = x @ W1_top (t<256); ubi = x @ W1_bot (t>=256, needb) ----
            if (tid < 256 || needb_s) {
                float a0 = 0.f, a1 = 0.f, a2 = 0.f, a3 = 0.f;
                #pragma unroll
                for (int q = 0; q < 32; ++q) {
                    const float4 xv = *reinterpret_cast<const float4*>(&x[q * 4]);
                    a0 += xv.x * w1reg[q * 4 + 0];
                    a1 += xv.y * w1reg[q * 4 + 1];
                    a2 += xv.z * w1reg[q * 4 + 2];
                    a3 += xv.w * w1reg[q * 4 + 3];
                }
                const float sres = (a0 + a1) + (a2 + a3);
                if (tid < 256) u[tid] = sres; else ubi[tid - 256] = sres;
            }
            __syncthreads();   // B1

            // ---- P2a: h1 rows = cand + sentinel (rows >= nrows zeroed) ----
            {
                const int nrows = ncand_s + 1;
                #pragma unroll
                for (int hh = 0; hh < 2; ++hh) {
                    const int idx = hh * 512 + tid;
                    const int r = idx >> 8, k = idx & 255;
                    float hv = 0.f;
                    if (r < nrows) {
                        const int v = (r < ncand_s) ? candlist[r] : -1;  // -1 = sentinel
                        float Bv = 0.f;
                        if (v > 0) Bv = (v == i && needb_s) ? ubi[k] : Bcur[v * H1n + k];
                        hv = fmaxf(u[k] + Bv + sb1[k], 0.f);
                    }
                    h1[r][k] = hv;
                }
            }
            __syncthreads();   // B2

            // ---- P2b: partials pa[kq][r][j] over k-quarter from swizzled W2T ----
            {
                const int kq = tid >> 7, j = tid & 127;
                const int sw = j & 7;
                float ac0 = 0.f, ac1 = 0.f, ac2 = 0.f, ac3 = 0.f;
                #pragma unroll
                for (int kk = 0; kk < 16; ++kk) {
                    const int cg = kq * 16 + kk;
                    const float4 wv = *reinterpret_cast<const float4*>(
                        &w2t[j * H1n + ((cg ^ sw) << 2)]);
                    const int k0 = cg << 2;
                    const float4 h0 = *reinterpret_cast<const float4*>(&h1[0][k0]);
                    const float4 h1v = *reinterpret_cast<const float4*>(&h1[1][k0]);
                    const float4 h2v = *reinterpret_cast<const float4*>(&h1[2][k0]);
                    const float4 h3v = *reinterpret_cast<const float4*>(&h1[3][k0]);
                    ac0 += h0.x * wv.x + h0.y * wv.y + h0.z * wv.z + h0.w * wv.w;
                    ac1 += h1v.x * wv.x + h1v.y * wv.y + h1v.z * wv.z + h1v.w * wv.w;
                    ac2 += h2v.x * wv.x + h2v.y * wv.y + h2v.z * wv.z + h2v.w * wv.w;
                    ac3 += h3v.x * wv.x + h3v.y * wv.y + h3v.z * wv.z + h3v.w * wv.w;
                }
                pa[kq][0][j] = ac0; pa[kq][1][j] = ac1;
                pa[kq][2][j] = ac2; pa[kq][3][j] = ac3;
            }
            __syncthreads();   // B3

            // ---- h2 + fused lk / act0 / act1 reductions ----
            {
                const int r = tid >> 7, j = tid & 127;
                const float v = pa[0][r][j] + pa[1][r][j] + pa[2][r][j] + pa[3][r][j]
                                + sb2[j];
                const float hval = fmaxf(v, 0.f);
                h2[r][j] = hval;
                float plk = hval * swlk[j];
                float p0  = hval * swact[2 * j];
                float p1  = hval * swact[2 * j + 1];
                #pragma unroll
                for (int off = 32; off; off >>= 1) {
                    plk += __shfl_down(plk, off);
                    p0  += __shfl_down(p0, off);
                    p1  += __shfl_down(p1, off);
                }
                if ((tid & 63) == 0) {
                    const int w = tid >> 6;
                    rb_lk[w] = plk; rb_a0[w] = p0; rb_a1[w] = p1;
                }
            }
            __syncthreads();   // B4

            // ---- argmax (first-max, index order) + action, single scalar phase ----
            if (tid == 0) {
                float lkv[4];
                #pragma unroll
                for (int r = 0; r < 4; ++r) lkv[r] = rb_lk[2 * r] + rb_lk[2 * r + 1] + sblk;
                float bv = -INFINITY; int ut = -1, rsel = -1;
                for (int r2 = 0; r2 < ncand_s; ++r2)
                    if (lkv[r2] > bv) { bv = lkv[r2]; ut = candlist[r2]; rsel = r2; }
                if (ut < 0 || lkv[ncand_s] > bv) ut = Nn;   // sentinel
                ut_s = ut;
                brk_s = (ut == Nn);
                if (!brk_s) {
                    rr_s = rsel;
                    const float a0 = rb_a0[2 * rsel] + rb_a0[2 * rsel + 1] + sba0;
                    const float a1 = rb_a1[2 * rsel] + rb_a1[2 * rsel + 1] + sba1;
                    at_s = (a1 > a0) ? 1 : 0;
                }
            }
            __syncthreads();   // B5
            if (brk_s) break;  // uniform: is_end -> done for remaining steps

            // ---- wide state update ----
            {
                const int utc = ut_s;
                const float at = (float)at_s;
                const bool selOld = (sel_mask[utc >> 6] >> (utc & 63)) & 1ULL;
                const float denom = cnt_s + at + 1.0f;
                if (tid < EE) {
                    const float g_ut = G0[utc * EE + tid];
                    const float futc = fmaxf(g_ut + sbe[tid], 0.f); // F0[utc] on the fly
                    const float z = (gsum[tid] + at * g_ut + G0[i * EE + tid]) / denom
                                    + sbe[tid];
                    float nx = fmaxf(z, 0.f);
                    if (utc == i) nx = futc;                 // .at[utc] write wins
                    x[tid] = nx;
                    if (utc != i) feat[i * EE + tid] = nx;
                    feat[utc * EE + tid] = futc;
                    rowf[tid] = futc;
                    if (at_s && !selOld) gsum[tid] += g_ut;
                }
                if (B0 != nullptr && tid < H1n)
                    Bcur[utc * H1n + tid] = B0[utc * H1n + tid];
            }
            __syncthreads();   // B6

            // ---- scalar update (+ Bcur[utc] recompute via regs if no B0 cache) ----
            if (tid == 0) {
                const int utc = ut_s;
                const bool selOld = (sel_mask[utc >> 6] >> (utc & 63)) & 1ULL;
                if (at_s && !selOld) { cnt_s += 1.f; sel_mask[utc >> 6] |= (1ULL << (utc & 63)); }
                cand_mask[utc >> 6] &= ~(1ULL << (utc & 63));
                upd_mask[i >> 6]   |= (1ULL << (i & 63));
                upd_mask[utc >> 6] |= (1ULL << (utc & 63));
                xdirty_s = (utc != i) ? 1 : 0;
                int nc = 0, selfc = 0;
                for (int w = 0; w < 2; ++w) {
                    unsigned long long m = cand_mask[w];
                    while (m && nc < 4) {
                        const int b = __builtin_ctzll(m);
                        const int v = w * 64 + b;
                        candlist[nc++] = v;
                        if (v == i) selfc = 1;
                        m &= m - 1;
                    }
                }
                ncand_s = nc; needb_s = selfc;
            }
            if (B0 == nullptr && tid >= 256) {   // rowf @ W1_bot via registers
                float a0 = 0.f, a1 = 0.f, a2 = 0.f, a3 = 0.f;
                #pragma unroll
                for (int q = 0; q < 32; ++q) {
                    const float4 xv = *reinterpret_cast<const float4*>(&rowf[q * 4]);
                    a0 += xv.x * w1reg[q * 4 + 0];
                    a1 += xv.y * w1reg[q * 4 + 1];
                    a2 += xv.z * w1reg[q * 4 + 2];
                    a3 += xv.w * w1reg[q * 4 + 3];
                }
                Bcur[ut_s * H1n + (tid - 256)] = (a0 + a1) + (a2 + a3);
            }
            __syncthreads();   // B7
        } // steps

        // node end: feature[i] left as embed(hv) -> refresh Bcur[i] via regs
        if (xdirty_s && tid >= 256) {
            float a0 = 0.f, a1 = 0.f, a2 = 0.f, a3 = 0.f;
            #pragma unroll
            for (int q = 0; q < 32; ++q) {
                const float4 xv = *reinterpret_cast<const float4*>(&x[q * 4]);
                a0 += xv.x * w1reg[q * 4 + 0];
                a1 += xv.y * w1reg[q * 4 + 1];
                a2 += xv.z * w1reg[q * 4 + 2];
                a3 += xv.w * w1reg[q * 4 + 3];
            }
            Bcur[i * H1n + (tid - 256)] = (a0 + a1) + (a2 + a3);
        }
        __syncthreads();       // node-end barrier (protects x before next init)
    } // nodes

    // out = where(updated, feat, 0) — in place on d_out
    for (int idx = tid; idx < Nn * EE; idx += 512) {
        const int n = idx >> 7;   // EE = 128
        const float v = feat[idx];
        feat[idx] = ((upd_mask[n >> 6] >> (n & 63)) & 1ULL) ? v : 0.f;
    }
}

// ---------------------------------------------------------------------------
extern "C" void kernel_launch(void* const* d_in, const int* in_sizes, int n_in,
                              void* d_out, int out_size, void* d_ws, size_t ws_size,
                              hipStream_t stream)
{
    (void)in_sizes; (void)n_in; (void)out_size;
    const float* adj  = (const float*)d_in[0];
    const float* fo   = (const float*)d_in[1];
    // d_in[2] = labels (unused by the forward pass)
    const float* We   = (const float*)d_in[3];
    const float* be   = (const float*)d_in[4];
    const float* W1   = (const float*)d_in[5];
    const float* b1   = (const float*)d_in[6];
    const float* W2   = (const float*)d_in[7];
    const float* b2   = (const float*)d_in[8];
    const float* wlk  = (const float*)d_in[9];
    const float* blkb = (const float*)d_in[10];
    const float* wact = (const float*)d_in[11];
    const float* bact = (const float*)d_in[12];

    float* ws   = (float*)d_ws;
    float* G0   = ws;                 // 128*128 floats (64 KB)
    float* Bcur = ws + 16384;         // 128*256 floats (128 KB)
    // Optional reset cache only if workspace is large enough (320 KB total)
    float* B0   = (ws_size >= (size_t)(64 + 128 + 128) * 1024) ? (ws + 49152) : nullptr;
    float* feat = (float*)d_out;      // evolving feature table lives in d_out (64 KB)

    hipLaunchKernelGGL(precomp1, dim3(Nn), dim3(EE), 0, stream, fo, We, be, G0, feat);
    hipLaunchKernelGGL(precomp2, dim3(Nn), dim3(H1n), 0, stream, G0, be, W1, Bcur, B0);
    hipLaunchKernelGGL(seqk, dim3(1), dim3(512), 0, stream,
                       adj, W1, b1, W2, b2, wlk, blkb, wact, bact, be,
                       G0, B0, feat, Bcur);
}